// Round 1
// baseline (196.224 us; speedup 1.0000x reference)
//
#include <hip/hip_runtime.h>
#include <hip/hip_fp16.h>

// SSM = batched cosine self-similarity.
// pianoroll: [8, 2048, 512] fp32 -> ssm [8, 2048, 2048] fp32.
// Pass 1: row-normalize, quantize to f16 into d_ws ([8*2048, 512] f16, 16.8 MB).
// Pass 2: per-batch NT-GEMM C = Xn * Xn^T via mfma_f32_16x16x32_f16,
//         m97-ladder structure: 128x128 tile, BK=32, global_load_lds width=16.

typedef _Float16 half8 __attribute__((ext_vector_type(8)));
typedef float floatx4 __attribute__((ext_vector_type(4)));

#define B_    8
#define T_    2048
#define D_    512

// async global->LDS, 16B per lane, LDS dest = wave-uniform base + lane*16
#define GLOAD_LDS16(g, l)                                                   \
    __builtin_amdgcn_global_load_lds(                                       \
        (const __attribute__((address_space(1))) void*)(g),                 \
        (__attribute__((address_space(3))) void*)(l), 16, 0, 0)

// ---------------------------------------------------------------------------
// Pass 1: one wave per row. Each lane holds 8 contiguous floats (2x float4),
// wave shuffle-reduce sum of squares, scale, store 8 f16 as one 16B store.
// ---------------------------------------------------------------------------
__global__ __launch_bounds__(256) void normalize_f16(
        const float* __restrict__ x, _Float16* __restrict__ xn) {
    const int row  = blockIdx.x * 4 + (threadIdx.x >> 6);
    const int lane = threadIdx.x & 63;
    const size_t base = (size_t)row * D_ + lane * 8;

    const float4* p = (const float4*)(x + base);
    float4 v0 = p[0];
    float4 v1 = p[1];
    float s = v0.x * v0.x + v0.y * v0.y + v0.z * v0.z + v0.w * v0.w
            + v1.x * v1.x + v1.y * v1.y + v1.z * v1.z + v1.w * v1.w;
    #pragma unroll
    for (int off = 32; off > 0; off >>= 1) s += __shfl_xor(s, off);

    const float sc = 1.0f / fmaxf(sqrtf(s), 1e-12f);
    half8 h;
    h[0] = (_Float16)(v0.x * sc);
    h[1] = (_Float16)(v0.y * sc);
    h[2] = (_Float16)(v0.z * sc);
    h[3] = (_Float16)(v0.w * sc);
    h[4] = (_Float16)(v1.x * sc);
    h[5] = (_Float16)(v1.y * sc);
    h[6] = (_Float16)(v1.z * sc);
    h[7] = (_Float16)(v1.w * sc);
    *(half8*)(xn + base) = h;
}

// ---------------------------------------------------------------------------
// Pass 2: C[b] = Xn[b] * Xn[b]^T.  Grid (16,16,8), block 256 (4 waves).
// 128x128 C-tile per block; each wave owns a 64x64 quadrant as 4x4 MFMAs.
// LDS tiles: 128 rows x 32 halves, row-major, NO padding (global_load_lds
// requires contiguous lane order).  K-loop: 512/32 = 16 iters.
// ---------------------------------------------------------------------------
__global__ __launch_bounds__(256) void ssm_gemm(
        const _Float16* __restrict__ xn, float* __restrict__ out) {
    __shared__ _Float16 ldsA[128 * 32];
    __shared__ _Float16 ldsB[128 * 32];

    const int m0 = blockIdx.x * 128;
    const int n0 = blockIdx.y * 128;
    const _Float16* __restrict__ Xb = xn + (size_t)blockIdx.z * T_ * D_;
    float* __restrict__ Cb = out + (size_t)blockIdx.z * T_ * T_;

    const int tid  = threadIdx.x;
    const int wave = tid >> 6;
    const int lane = tid & 63;
    const int wrow = (wave >> 1) * 64;   // A-row quadrant
    const int wcol = (wave & 1) * 64;    // B-row (C-col) quadrant

    // staging: wave w, inst s covers rows [w*32 + s*16, +16), lane -> row w*32+s*16+(lane>>2), chunk (lane&3)*8 halves
    const int srow = wave * 32 + (lane >> 2);
    const _Float16* ga = Xb + (size_t)(m0 + srow) * D_ + (lane & 3) * 8;
    const _Float16* gb = Xb + (size_t)(n0 + srow) * D_ + (lane & 3) * 8;
    _Float16* la = ldsA + wave * 1024;   // 2 insts x 64 lanes x 8 halves = 1024 halves/wave
    _Float16* lb = ldsB + wave * 1024;

    // fragment addressing: A[m][k] m=lane&15, k=(lane>>4)*8 + j  (same for B rows)
    const int fr = lane & 15;
    const int fk = (lane >> 4) * 8;

    floatx4 acc[4][4] = {};

    for (int k0 = 0; k0 < D_; k0 += 32) {
        GLOAD_LDS16(ga + k0,            la);
        GLOAD_LDS16(ga + k0 + 16 * D_,  la + 512);
        GLOAD_LDS16(gb + k0,            lb);
        GLOAD_LDS16(gb + k0 + 16 * D_,  lb + 512);
        __syncthreads();

        half8 af[4], bf[4];
        #pragma unroll
        for (int i = 0; i < 4; ++i) {
            af[i] = *(const half8*)(ldsA + (wrow + i * 16 + fr) * 32 + fk);
            bf[i] = *(const half8*)(ldsB + (wcol + i * 16 + fr) * 32 + fk);
        }
        #pragma unroll
        for (int i = 0; i < 4; ++i)
            #pragma unroll
            for (int j = 0; j < 4; ++j)
                acc[i][j] = __builtin_amdgcn_mfma_f32_16x16x32_f16(
                    af[i], bf[j], acc[i][j], 0, 0, 0);
        __syncthreads();
    }

    // epilogue: C/D layout col=lane&15, row=(lane>>4)*4 + reg
    const int crow = m0 + wrow + (lane >> 4) * 4;
    const int ccol = n0 + wcol + (lane & 15);
    #pragma unroll
    for (int i = 0; i < 4; ++i)
        #pragma unroll
        for (int j = 0; j < 4; ++j)
            #pragma unroll
            for (int r = 0; r < 4; ++r)
                Cb[(size_t)(crow + i * 16 + r) * T_ + (ccol + j * 16)] = acc[i][j][r];
}

extern "C" void kernel_launch(void* const* d_in, const int* in_sizes, int n_in,
                              void* d_out, int out_size, void* d_ws, size_t ws_size,
                              hipStream_t stream) {
    const float* x = (const float*)d_in[0];
    float* out = (float*)d_out;
    _Float16* xn = (_Float16*)d_ws;   // 8*2048*512 f16 = 16.8 MB

    normalize_f16<<<dim3(B_ * T_ / 4), dim3(256), 0, stream>>>(x, xn);
    ssm_gemm<<<dim3(T_ / 128, T_ / 128, B_), dim3(256), 0, stream>>>(xn, out);
}